// Round 2
// baseline (240.082 us; speedup 1.0000x reference)
//
#include <hip/hip_runtime.h>
#include <hip/hip_cooperative_groups.h>
#include <math.h>

namespace cg = cooperative_groups;

#define B_  16
#define C_  64
#define E_  5

typedef __bf16  bf16x8 __attribute__((ext_vector_type(8)));
typedef float   f32x4  __attribute__((ext_vector_type(4)));

// ---- ws byte offsets ----
// wEffB: [e(5)][g(2)][tap(9)][q(4)][co(64)][j(8)] ushort = 184320 shorts = 368640 B
#define WS_WEFFB   0
#define WS_BIAS    368640      // float[5*64] -> ends 369920
#define WS_POOL    369920      // float[16*64] (zeroed each call) -> 374016
#define WS_Z       374016      // float[16] (zeroed each call) -> 374080
#define WS_EIDX    374080      // int[16] -> 374144
#define WS_XT      374144      // bf16 x_t [b][row][col][ci] = 33554432 B -> 33928576
#define WS_EXP     33928576ull // bf16 exp [b][co][row][col] = 33554432 B -> 67483008
#define WS_NEED_A  67483008ull

static __device__ __forceinline__ unsigned short f2bf(float f) {
    unsigned int u = __float_as_uint(f);
    unsigned int r = (u + 0x7fffu + ((u >> 16) & 1u)) >> 16;  // RNE
    return (unsigned short)r;
}

// ===========================================================================
// ============ PATH 1: single fused cooperative kernel ======================
// ===========================================================================
// 1024 blocks x 256 threads; requires 4 blocks/CU co-residency (checked on host).
__global__ __launch_bounds__(256, 4) void fused_moe(
        const float* __restrict__ x, const float* __restrict__ noise,
        const float* __restrict__ w_gate, const float* __restrict__ b_gate,
        const float* __restrict__ w_noise, const float* __restrict__ b_noise,
        const float* __restrict__ w1, const float* __restrict__ w_cd,
        const float* __restrict__ w_hd, const float* __restrict__ w_vd,
        const float* __restrict__ w_ad,
        const float* __restrict__ b1, const float* __restrict__ b_cd,
        const float* __restrict__ b_hd, const float* __restrict__ b_vd,
        const float* __restrict__ b_ad,
        unsigned short* __restrict__ wEffB, float* __restrict__ biasEff,
        float* __restrict__ pooled, float* __restrict__ Z,
        int* __restrict__ eidx, unsigned short* __restrict__ x_t,
        float* __restrict__ out) {

    cg::grid_group grid = cg::this_grid();
    int t = threadIdx.x;
    int blk = blockIdx.x;

    // union'd LDS: phase1 T[128][72] (18432 B) / phase3 Xs (26112 B) / small bufs
    __shared__ __align__(16) unsigned short SMEM[6 * 4 * 68 * 8];  // 26112 B

    // ---------------- Phase 1a: build effective weights (1 elem/thread) ----
    {
        int gid = blk * 256 + t;
        if (gid < E_ * 36864) {
            int e   = gid / 36864;
            int r   = gid % 36864;
            int g   = r / 18432;
            int r2  = r % 18432;
            int tap = r2 / 2048;
            int r3  = r2 % 2048;
            int q   = r3 / 512;
            int r4  = r3 % 512;
            int co  = r4 / 8;
            int j   = r4 % 8;
            int ci = g * 32 + q * 8 + j;
            int base9 = (co * 64 + ci) * 9;
            int base3 = (co * 64 + ci) * 3;
            float v = 0.f;
            if (e == 0) {
                v = w1[base9 + tap];
            } else if (e == 1) {
                if (tap == 4) {
                    float s = 0.f;
                    #pragma unroll
                    for (int k = 0; k < 9; k++) s += w_cd[base9 + k];
                    v = w_cd[base9 + 4] - s;
                } else {
                    v = w_cd[base9 + tap];
                }
            } else if (e == 2) {
                int m = tap % 3;
                if (m == 0) v = w_hd[base3 + tap / 3];
                else if (m == 2) v = -w_hd[base3 + tap / 3];
            } else if (e == 3) {
                if (tap < 3) v = w_vd[base3 + tap];
                else if (tap >= 6) v = -w_vd[base3 + tap - 6];
            } else {
                const int PERM[9] = {3, 0, 1, 6, 4, 2, 7, 8, 5};
                v = w_ad[base9 + tap] - w_ad[base9 + PERM[tap]];
            }
            wEffB[gid] = f2bf(v);
        } else if (gid < E_ * 36864 + E_ * 64) {
            int jj = gid - E_ * 36864;
            int e = jj / 64, co = jj % 64;
            const float* bs;
            switch (e) {
                case 0: bs = b1; break;
                case 1: bs = b_cd; break;
                case 2: bs = b_hd; break;
                case 3: bs = b_vd; break;
                default: bs = b_ad; break;
            }
            biasEff[jj] = bs[co];
        }
    }

    // ---------------- Phase 1b: transpose fp32 NCHW -> bf16 NHWC + pooling --
    {
        int wave = t >> 6, l = t & 63;
        int half = l >> 5;
        int c4 = l & 31;
        unsigned short (*T)[72] = (unsigned short (*)[72])SMEM;

        for (int ii = 0; ii < 2; ii++) {
            int task = blk * 2 + ii;              // 2048 (b,row) tasks
            int b = task >> 7, row = task & 127;
            const float* xb = x + (size_t)b * (64 * 16384) + row * 128;

            #pragma unroll
            for (int it = 0; it < 8; it++) {
                int ci = wave * 16 + it * 2 + half;
                float4 v = *(const float4*)(xb + (size_t)ci * 16384 + c4 * 4);
                float p = v.x + v.y + v.z + v.w;
                p += __shfl_down(p, 16, 32);
                p += __shfl_down(p, 8, 32);
                p += __shfl_down(p, 4, 32);
                p += __shfl_down(p, 2, 32);
                p += __shfl_down(p, 1, 32);
                if (c4 == 0) atomicAdd(&pooled[b * 64 + ci], p * (1.0f / 16384.0f));
                int colb = c4 * 4;
                T[colb + 0][ci] = f2bf(v.x);
                T[colb + 1][ci] = f2bf(v.y);
                T[colb + 2][ci] = f2bf(v.z);
                T[colb + 3][ci] = f2bf(v.w);
            }
            __syncthreads();

            unsigned short* dst = x_t + ((size_t)(b * 128 + row) * 128) * 64;
            #pragma unroll
            for (int k = 0; k < 4; k++) {
                int chunk = t + k * 256;
                int col = chunk >> 3, c8 = chunk & 7;
                uint4 vv = *(const uint4*)&T[col][c8 * 8];
                *(uint4*)(dst + col * 64 + c8 * 8) = vv;
            }
            __syncthreads();
        }
    }

    __threadfence();
    grid.sync();
    __threadfence();

    // ---------------- Phase 2: noisy top-1 routing (block 0 only) ----------
    if (blk == 0) {
        float* vbuf = (float*)SMEM;               // 80 floats
        if (t < B_ * E_) {
            int b = t / E_, e = t % E_;
            float lg = b_gate[e], nz = b_noise[e];
            for (int c = 0; c < C_; c++) {
                float pv = pooled[b * C_ + c];
                lg += pv * w_gate[c * E_ + e];
                nz += pv * w_noise[c * E_ + e];
            }
            float sp = log1pf(expf(nz));
            vbuf[t] = lg + noise[b * E_ + e] * sp;
        }
        __syncthreads();
        if (t < B_) {
            float best = -1e30f; int bi = 0;
            #pragma unroll
            for (int e = 0; e < E_; e++) {
                float v = vbuf[t * E_ + e];
                if (v > best) { best = v; bi = e; }
            }
            eidx[t] = bi;
        }
    }

    __threadfence();
    grid.sync();
    __threadfence();

    // ---------------- Phase 3: conv (implicit GEMM, MFMA) ------------------
    int b   = blk >> 6;
    int rem = blk & 63;
    int rg  = rem >> 1;
    int ch  = rem & 1;
    int wave = t >> 6, lane = t & 63;
    int ln = lane & 15, q = lane >> 4;
    int e = eidx[b];

    f32x4 acc[4][4];
    #pragma unroll
    for (int i = 0; i < 4; i++)
        #pragma unroll
        for (int jn = 0; jn < 4; jn++)
            acc[i][jn] = (f32x4){0.f, 0.f, 0.f, 0.f};

    const unsigned short* xb = x_t + (size_t)b * (128 * 128 * 64);
    const unsigned short* we = wEffB + (size_t)e * 36864;

    for (int g = 0; g < 2; g++) {
        for (int j = t; j < 1584; j += 256) {
            int xr = j / 264;
            int r2 = j % 264;
            int col = r2 >> 2;
            int qq = r2 & 3;
            int irow = rg * 4 - 1 + xr;
            int icol = ch * 64 - 1 + col;
            uint4 v = make_uint4(0, 0, 0, 0);
            if ((unsigned)irow < 128u && (unsigned)icol < 128u)
                v = *(const uint4*)(xb + ((size_t)irow * 128 + icol) * 64 + g * 32 + qq * 8);
            *(uint4*)&SMEM[((xr * 4 + qq) * 68 + col) * 8] = v;
        }
        __syncthreads();

        const unsigned short* wg = we + g * 18432;
        #pragma unroll
        for (int tap = 0; tap < 9; tap++) {
            int dr = tap / 3, dc = tap % 3;
            bf16x8 af[4], bfr[4];
            #pragma unroll
            for (int mt = 0; mt < 4; mt++)
                af[mt] = *(const bf16x8*)(wg + ((tap * 4 + q) * 64 + mt * 16 + ln) * 8);
            int xr = wave + dr;
            #pragma unroll
            for (int t4 = 0; t4 < 4; t4++)
                bfr[t4] = *(const bf16x8*)&SMEM[((xr * 4 + q) * 68 + t4 * 16 + ln + dc) * 8];
            #pragma unroll
            for (int mt = 0; mt < 4; mt++)
                #pragma unroll
                for (int t4 = 0; t4 < 4; t4++)
                    acc[mt][t4] = __builtin_amdgcn_mfma_f32_16x16x32_bf16(
                        af[mt], bfr[t4], acc[mt][t4], 0, 0, 0);
        }
        __syncthreads();
    }

    // epilogue: bias + exp (kept in registers) + per-example Z atomic
    int orow = rg * 4 + wave;
    float bsum = 0.f;
    #pragma unroll
    for (int mt = 0; mt < 4; mt++) {
        float4 bias4 = *(const float4*)(biasEff + e * 64 + mt * 16 + q * 4);
        const float* bp = (const float*)&bias4;
        #pragma unroll
        for (int r = 0; r < 4; r++) {
            #pragma unroll
            for (int t4 = 0; t4 < 4; t4++) {
                float ev = __expf(acc[mt][t4][r] + bp[r]);
                acc[mt][t4][r] = ev;
                bsum += ev;
            }
        }
    }
    for (int off = 32; off; off >>= 1) bsum += __shfl_down(bsum, off, 64);
    {
        float* zsF = (float*)SMEM;
        if (lane == 0) zsF[wave] = bsum;
        __syncthreads();
        if (t == 0) atomicAdd(&Z[b], zsF[0] + zsF[1] + zsF[2] + zsF[3]);
    }

    __threadfence();
    grid.sync();
    __threadfence();

    // ---------------- Phase 4: scale from registers, store fp32 ------------
    float sinv = 1.0f / Z[b];
    size_t obase = (size_t)b * (64 * 16384);
    #pragma unroll
    for (int mt = 0; mt < 4; mt++) {
        #pragma unroll
        for (int r = 0; r < 4; r++) {
            int co = mt * 16 + q * 4 + r;
            size_t cb = obase + (size_t)co * 16384 + (size_t)orow * 128;
            #pragma unroll
            for (int t4 = 0; t4 < 4; t4++) {
                int ocol = ch * 64 + t4 * 16 + ln;
                out[cb + ocol] = acc[mt][t4][r] * sinv;
            }
        }
    }
}

// ===========================================================================
// ============ PATH 2: split kernels (fallback, known-good) =================
// ===========================================================================
__global__ __launch_bounds__(256) void transpose_pool_kernel(
        const float* __restrict__ x, unsigned short* __restrict__ x_t,
        float* __restrict__ pooled) {
    int bid = blockIdx.x;
    int b = bid >> 7, row = bid & 127;
    int t = threadIdx.x;
    int wave = t >> 6, l = t & 63;
    int half = l >> 5;
    int c4 = l & 31;

    __shared__ unsigned short T[128][72];

    const float* xb = x + (size_t)b * (64 * 16384) + row * 128;

    #pragma unroll
    for (int it = 0; it < 8; it++) {
        int ci = wave * 16 + it * 2 + half;
        float4 v = *(const float4*)(xb + (size_t)ci * 16384 + c4 * 4);
        float p = v.x + v.y + v.z + v.w;
        p += __shfl_down(p, 16, 32);
        p += __shfl_down(p, 8, 32);
        p += __shfl_down(p, 4, 32);
        p += __shfl_down(p, 2, 32);
        p += __shfl_down(p, 1, 32);
        if (c4 == 0) atomicAdd(&pooled[b * 64 + ci], p * (1.0f / 16384.0f));
        int colb = c4 * 4;
        T[colb + 0][ci] = f2bf(v.x);
        T[colb + 1][ci] = f2bf(v.y);
        T[colb + 2][ci] = f2bf(v.z);
        T[colb + 3][ci] = f2bf(v.w);
    }
    __syncthreads();

    unsigned short* dst = x_t + ((size_t)(b * 128 + row) * 128) * 64;
    #pragma unroll
    for (int k = 0; k < 4; k++) {
        int chunk = t + k * 256;
        int col = chunk >> 3, c8 = chunk & 7;
        uint4 vv = *(const uint4*)&T[col][c8 * 8];
        *(uint4*)(dst + col * 64 + c8 * 8) = vv;
    }
}

__global__ void route_kernel(const float* __restrict__ pooled,
                             const float* __restrict__ noise,
                             const float* __restrict__ w_gate, const float* __restrict__ b_gate,
                             const float* __restrict__ w_noise, const float* __restrict__ b_noise,
                             int* __restrict__ expert_idx) {
    int b = threadIdx.x;
    if (b >= B_) return;
    float best = -1e30f;
    int bi = 0;
    for (int e = 0; e < E_; e++) {
        float lg = b_gate[e], nz = b_noise[e];
        for (int c = 0; c < C_; c++) {
            float pv = pooled[b * C_ + c];
            lg += pv * w_gate[c * E_ + e];
            nz += pv * w_noise[c * E_ + e];
        }
        float sp = log1pf(expf(nz));
        float v = lg + noise[b * E_ + e] * sp;
        if (v > best) { best = v; bi = e; }
    }
    expert_idx[b] = bi;
}

__global__ void build_w_kernel(const float* __restrict__ w1, const float* __restrict__ w_cd,
                               const float* __restrict__ w_hd, const float* __restrict__ w_vd,
                               const float* __restrict__ w_ad,
                               const float* __restrict__ b1, const float* __restrict__ b_cd,
                               const float* __restrict__ b_hd, const float* __restrict__ b_vd,
                               const float* __restrict__ b_ad,
                               unsigned short* __restrict__ wEffB, float* __restrict__ biasEff) {
    int gid = blockIdx.x * 256 + threadIdx.x;
    if (gid < E_ * 36864) {
        int e   = gid / 36864;
        int r   = gid % 36864;
        int g   = r / 18432;
        int r2  = r % 18432;
        int tap = r2 / 2048;
        int r3  = r2 % 2048;
        int q   = r3 / 512;
        int r4  = r3 % 512;
        int co  = r4 / 8;
        int j   = r4 % 8;
        int ci = g * 32 + q * 8 + j;
        int base9 = (co * 64 + ci) * 9;
        int base3 = (co * 64 + ci) * 3;
        float v = 0.f;
        if (e == 0) {
            v = w1[base9 + tap];
        } else if (e == 1) {
            if (tap == 4) {
                float s = 0.f;
                #pragma unroll
                for (int k = 0; k < 9; k++) s += w_cd[base9 + k];
                v = w_cd[base9 + 4] - s;
            } else {
                v = w_cd[base9 + tap];
            }
        } else if (e == 2) {
            int m = tap % 3;
            if (m == 0) v = w_hd[base3 + tap / 3];
            else if (m == 2) v = -w_hd[base3 + tap / 3];
        } else if (e == 3) {
            if (tap < 3) v = w_vd[base3 + tap];
            else if (tap >= 6) v = -w_vd[base3 + tap - 6];
        } else {
            const int PERM[9] = {3, 0, 1, 6, 4, 2, 7, 8, 5};
            v = w_ad[base9 + tap] - w_ad[base9 + PERM[tap]];
        }
        wEffB[gid] = f2bf(v);
    } else if (gid < E_ * 36864 + E_ * 64) {
        int jj = gid - E_ * 36864;
        int e = jj / 64, co = jj % 64;
        const float* bs;
        switch (e) {
            case 0: bs = b1; break;
            case 1: bs = b_cd; break;
            case 2: bs = b_hd; break;
            case 3: bs = b_vd; break;
            default: bs = b_ad; break;
        }
        biasEff[jj] = bs[co];
    }
}

// conv: A read direct from global (L2-hot), X staged in LDS. LDS 26 KB -> ~5 blk/CU.
__global__ __launch_bounds__(256, 4) void conv_mfma_kernel(
        const unsigned short* __restrict__ x_t, const unsigned short* __restrict__ wEffB,
        const float* __restrict__ biasEff, const int* __restrict__ expert_idx,
        unsigned short* __restrict__ expw, float* __restrict__ outf,
        float* __restrict__ Z, int direct_f32) {
    int bid = blockIdx.x;
    int b = bid >> 6;
    int rem = bid & 63;
    int rg = rem >> 1;
    int ch = rem & 1;

    int t = threadIdx.x;
    int wave = t >> 6;
    int lane = t & 63;
    int ln = lane & 15;
    int q = lane >> 4;

    int e = expert_idx[b];

    __shared__ __align__(16) unsigned short Xs[6 * 4 * 68 * 8];     // 26112 B
    __shared__ float zs[4];

    f32x4 acc[4][4];
    #pragma unroll
    for (int i = 0; i < 4; i++)
        #pragma unroll
        for (int jn = 0; jn < 4; jn++)
            acc[i][jn] = (f32x4){0.f, 0.f, 0.f, 0.f};

    const unsigned short* xb = x_t + (size_t)b * (128 * 128 * 64);
    const unsigned short* we = wEffB + (size_t)e * 36864;

    for (int g = 0; g < 2; g++) {
        for (int j = t; j < 1584; j += 256) {
            int xr = j / 264;
            int r2 = j % 264;
            int col = r2 >> 2;
            int qq = r2 & 3;
            int irow = rg * 4 - 1 + xr;
            int icol = ch * 64 - 1 + col;
            uint4 v = make_uint4(0, 0, 0, 0);
            if ((unsigned)irow < 128u && (unsigned)icol < 128u)
                v = *(const uint4*)(xb + ((size_t)irow * 128 + icol) * 64 + g * 32 + qq * 8);
            *(uint4*)&Xs[((xr * 4 + qq) * 68 + col) * 8] = v;
        }
        __syncthreads();

        const unsigned short* wg = we + g * 18432;
        #pragma unroll
        for (int tap = 0; tap < 9; tap++) {
            int dr = tap / 3, dc = tap % 3;
            bf16x8 af[4], bfr[4];
            #pragma unroll
            for (int mt = 0; mt < 4; mt++)
                af[mt] = *(const bf16x8*)(wg + ((tap * 4 + q) * 64 + mt * 16 + ln) * 8);
            int xr = wave + dr;
            #pragma unroll
            for (int t4 = 0; t4 < 4; t4++)
                bfr[t4] = *(const bf16x8*)&Xs[((xr * 4 + q) * 68 + t4 * 16 + ln + dc) * 8];
            #pragma unroll
            for (int mt = 0; mt < 4; mt++)
                #pragma unroll
                for (int t4 = 0; t4 < 4; t4++)
                    acc[mt][t4] = __builtin_amdgcn_mfma_f32_16x16x32_bf16(
                        af[mt], bfr[t4], acc[mt][t4], 0, 0, 0);
        }
        __syncthreads();
    }

    int orow = rg * 4 + wave;
    float bsum = 0.f;
    size_t obase = (size_t)b * (64 * 16384);
    #pragma unroll
    for (int mt = 0; mt < 4; mt++) {
        float4 bias4 = *(const float4*)(biasEff + e * 64 + mt * 16 + q * 4);
        const float* bp = (const float*)&bias4;
        #pragma unroll
        for (int r = 0; r < 4; r++) {
            int co = mt * 16 + q * 4 + r;
            size_t cb = obase + (size_t)co * 16384 + (size_t)orow * 128;
            #pragma unroll
            for (int t4 = 0; t4 < 4; t4++) {
                float ev = __expf(acc[mt][t4][r] + bp[r]);
                bsum += ev;
                int ocol = ch * 64 + t4 * 16 + ln;
                if (direct_f32) outf[cb + ocol] = ev;
                else            expw[cb + ocol] = f2bf(ev);
            }
        }
    }
    for (int off = 32; off; off >>= 1) bsum += __shfl_down(bsum, off, 64);
    if (lane == 0) zs[wave] = bsum;
    __syncthreads();
    if (t == 0) atomicAdd(&Z[b], zs[0] + zs[1] + zs[2] + zs[3]);
}

__global__ __launch_bounds__(256) void scale_bf16_kernel(
        const unsigned short* __restrict__ expw, const float* __restrict__ Z,
        float* __restrict__ out) {
    int gid = blockIdx.x * 256 + threadIdx.x;
    int b = gid >> 17;
    __shared__ float sinv;
    if (threadIdx.x == 0) sinv = 1.0f / Z[b];
    __syncthreads();
    uint4 r = ((const uint4*)expw)[gid];
    float4 o0, o1;
    o0.x = __uint_as_float(r.x << 16) * sinv;
    o0.y = __uint_as_float(r.x & 0xffff0000u) * sinv;
    o0.z = __uint_as_float(r.y << 16) * sinv;
    o0.w = __uint_as_float(r.y & 0xffff0000u) * sinv;
    o1.x = __uint_as_float(r.z << 16) * sinv;
    o1.y = __uint_as_float(r.z & 0xffff0000u) * sinv;
    o1.z = __uint_as_float(r.w << 16) * sinv;
    o1.w = __uint_as_float(r.w & 0xffff0000u) * sinv;
    ((float4*)out)[gid * 2] = o0;
    ((float4*)out)[gid * 2 + 1] = o1;
}

__global__ __launch_bounds__(256) void scale_inplace_kernel(
        float* __restrict__ out, const float* __restrict__ Z) {
    int gid = blockIdx.x * 256 + threadIdx.x;
    int b = gid >> 18;
    __shared__ float sinv;
    if (threadIdx.x == 0) sinv = 1.0f / Z[b];
    __syncthreads();
    float4 v = ((float4*)out)[gid];
    v.x *= sinv; v.y *= sinv; v.z *= sinv; v.w *= sinv;
    ((float4*)out)[gid] = v;
}

// ---------------------------------------------------------------------------
extern "C" void kernel_launch(void* const* d_in, const int* in_sizes, int n_in,
                              void* d_out, int out_size, void* d_ws, size_t ws_size,
                              hipStream_t stream) {
    const float* x       = (const float*)d_in[0];
    const float* noise   = (const float*)d_in[1];
    const float* w_gate  = (const float*)d_in[2];
    const float* b_gate  = (const float*)d_in[3];
    const float* w_noise = (const float*)d_in[4];
    const float* b_noise = (const float*)d_in[5];
    const float* w1      = (const float*)d_in[6];
    const float* b1      = (const float*)d_in[7];
    const float* w_cd    = (const float*)d_in[8];
    const float* b_cd    = (const float*)d_in[9];
    const float* w_hd    = (const float*)d_in[10];
    const float* b_hd    = (const float*)d_in[11];
    const float* w_vd    = (const float*)d_in[12];
    const float* b_vd    = (const float*)d_in[13];
    const float* w_ad    = (const float*)d_in[14];
    const float* b_ad    = (const float*)d_in[15];

    char* ws = (char*)d_ws;
    unsigned short* wEffB   = (unsigned short*)(ws + WS_WEFFB);
    float*          biasEff = (float*)(ws + WS_BIAS);
    float*          pooled  = (float*)(ws + WS_POOL);
    float*          Zbuf    = (float*)(ws + WS_Z);
    int*            eidx    = (int*)(ws + WS_EIDX);
    unsigned short* x_t     = (unsigned short*)(ws + WS_XT);
    unsigned short* expw    = (unsigned short*)(ws + WS_EXP);

    float* out = (float*)d_out;

    // zero pooled + Z (contiguous 4160 B)
    hipMemsetAsync(pooled, 0, 4160, stream);

    // --- decide path: cooperative fused kernel needs 4 blocks/CU co-resident ---
    int nb = 0;
    hipError_t qerr = hipOccupancyMaxActiveBlocksPerMultiprocessor(
        &nb, (const void*)fused_moe, 256, 0);
    bool coop = (qerr == hipSuccess) && (nb >= 4);

    if (coop) {
        void* kargs[] = {
            (void*)&x, (void*)&noise,
            (void*)&w_gate, (void*)&b_gate, (void*)&w_noise, (void*)&b_noise,
            (void*)&w1, (void*)&w_cd, (void*)&w_hd, (void*)&w_vd, (void*)&w_ad,
            (void*)&b1, (void*)&b_cd, (void*)&b_hd, (void*)&b_vd, (void*)&b_ad,
            (void*)&wEffB, (void*)&biasEff, (void*)&pooled, (void*)&Zbuf,
            (void*)&eidx, (void*)&x_t, (void*)&out
        };
        hipError_t lerr = hipLaunchCooperativeKernel((void*)fused_moe, dim3(1024),
                                                     dim3(256), kargs, 0, stream);
        if (lerr != hipSuccess) coop = false;   // fall back within same capture
    }

    if (!coop) {
        int mode_a = (ws_size >= WS_NEED_A) ? 1 : 0;
        transpose_pool_kernel<<<B_ * 128, 256, 0, stream>>>(x, x_t, pooled);
        route_kernel<<<1, 64, 0, stream>>>(pooled, noise, w_gate, b_gate, w_noise, b_noise, eidx);
        build_w_kernel<<<(E_ * 36864 + E_ * 64 + 255) / 256, 256, 0, stream>>>(
            w1, w_cd, w_hd, w_vd, w_ad, b1, b_cd, b_hd, b_vd, b_ad, wEffB, biasEff);
        conv_mfma_kernel<<<1024, 256, 0, stream>>>(x_t, wEffB, biasEff, eidx,
                                                   expw, out, Zbuf, mode_a ? 0 : 1);
        if (mode_a)
            scale_bf16_kernel<<<8192, 256, 0, stream>>>(expw, Zbuf, out);
        else
            scale_inplace_kernel<<<16384, 256, 0, stream>>>(out, Zbuf);
    }
}

// Round 3
// 220.132 us; speedup vs baseline: 1.0906x; 1.0906x over previous
//
#include <hip/hip_runtime.h>
#include <math.h>

#define B_  16
#define C_  64
#define E_  5

typedef __bf16  bf16x8 __attribute__((ext_vector_type(8)));
typedef float   f32x4  __attribute__((ext_vector_type(4)));

// ---- ws byte offsets ----
// wEffB: [e(5)][g(2)][tap(9)][q(4)][co(64)][j(8)] ushort = 184320 shorts = 368640 B
#define WS_WEFFB   0
#define WS_BIAS    368640      // float[5*64] -> ends 369920
#define WS_POOL    369920      // float[16*64] (zeroed each call) -> 374016
#define WS_Z       374016      // float[16] (zeroed each call) -> 374080
#define WS_EIDX    374080      // int[16] -> 374144
#define WS_XT      374144      // bf16 x_t [b][row][col][ci] = 33554432 B -> 33928576
#define WS_EXP     33928576ull // bf16 exp [b][co][row][col] = 33554432 B -> 67483008
#define WS_NEED_A  67483008ull

static __device__ __forceinline__ unsigned short f2bf(float f) {
    unsigned int u = __float_as_uint(f);
    unsigned int r = (u + 0x7fffu + ((u >> 16) & 1u)) >> 16;  // RNE
    return (unsigned short)r;
}

// ---------------------------------------------------------------------------
// Kernel 1: fused transpose (fp32 NCHW -> bf16 NHWC) + global-mean pooling
// grid: (b*128 + row) = 2048 blocks, 256 thr  [known-good]
__global__ __launch_bounds__(256) void transpose_pool_kernel(
        const float* __restrict__ x, unsigned short* __restrict__ x_t,
        float* __restrict__ pooled) {
    int bid = blockIdx.x;
    int b = bid >> 7, row = bid & 127;
    int t = threadIdx.x;
    int wave = t >> 6, l = t & 63;
    int half = l >> 5;        // which of 2 ci per iter
    int c4 = l & 31;          // float4 column chunk

    __shared__ unsigned short T[128][72];   // [col][ci], padded

    const float* xb = x + (size_t)b * (64 * 16384) + row * 128;

    #pragma unroll
    for (int it = 0; it < 8; it++) {
        int ci = wave * 16 + it * 2 + half;
        float4 v = *(const float4*)(xb + (size_t)ci * 16384 + c4 * 4);
        float p = v.x + v.y + v.z + v.w;
        p += __shfl_down(p, 16, 32);
        p += __shfl_down(p, 8, 32);
        p += __shfl_down(p, 4, 32);
        p += __shfl_down(p, 2, 32);
        p += __shfl_down(p, 1, 32);
        if (c4 == 0) atomicAdd(&pooled[b * 64 + ci], p * (1.0f / 16384.0f));
        int colb = c4 * 4;
        T[colb + 0][ci] = f2bf(v.x);
        T[colb + 1][ci] = f2bf(v.y);
        T[colb + 2][ci] = f2bf(v.z);
        T[colb + 3][ci] = f2bf(v.w);
    }
    __syncthreads();

    unsigned short* dst = x_t + ((size_t)(b * 128 + row) * 128) * 64;
    #pragma unroll
    for (int k = 0; k < 4; k++) {
        int chunk = t + k * 256;          // 1024 chunks of 16B
        int col = chunk >> 3, c8 = chunk & 7;
        uint4 vv = *(const uint4*)&T[col][c8 * 8];
        *(uint4*)(dst + col * 64 + c8 * 8) = vv;
    }
}

// ---------------------------------------------------------------------------
// Kernel 2: fused routing (blocks 0..15, lane-parallel) + build_w (blocks 16+)
// grid: 16 + 722 = 738 blocks, 256 thr
__global__ __launch_bounds__(256) void prep_kernel(
        const float* __restrict__ pooled, const float* __restrict__ noise,
        const float* __restrict__ w_gate, const float* __restrict__ b_gate,
        const float* __restrict__ w_noise, const float* __restrict__ b_noise,
        const float* __restrict__ w1, const float* __restrict__ w_cd,
        const float* __restrict__ w_hd, const float* __restrict__ w_vd,
        const float* __restrict__ w_ad,
        const float* __restrict__ b1, const float* __restrict__ b_cd,
        const float* __restrict__ b_hd, const float* __restrict__ b_vd,
        const float* __restrict__ b_ad,
        int* __restrict__ expert_idx,
        unsigned short* __restrict__ wEffB, float* __restrict__ biasEff) {
    int blk = blockIdx.x;
    int t = threadIdx.x;

    if (blk < B_) {
        // ---- routing for example b = blk: lanes 0..63 parallel over channels ----
        if (t < 64) {
            int b = blk;
            float pv = pooled[b * C_ + t];
            float ge[E_], ne[E_];
            #pragma unroll
            for (int e = 0; e < E_; e++) {
                ge[e] = pv * w_gate[t * E_ + e];
                ne[e] = pv * w_noise[t * E_ + e];
            }
            #pragma unroll
            for (int off = 32; off; off >>= 1) {
                #pragma unroll
                for (int e = 0; e < E_; e++) {
                    ge[e] += __shfl_xor(ge[e], off, 64);
                    ne[e] += __shfl_xor(ne[e], off, 64);
                }
            }
            if (t == 0) {
                float best = -1e30f; int bi = 0;
                #pragma unroll
                for (int e = 0; e < E_; e++) {
                    float lg = ge[e] + b_gate[e];
                    float nz = ne[e] + b_noise[e];
                    float sp = log1pf(expf(nz));
                    float v = lg + noise[b * E_ + e] * sp;
                    if (v > best) { best = v; bi = e; }   // first max wins (matches top_k)
                }
                expert_idx[b] = bi;
            }
        }
        return;
    }

    // ---- build effective weights ----
    int gid = (blk - B_) * 256 + t;
    if (gid < E_ * 36864) {
        int e   = gid / 36864;
        int r   = gid % 36864;
        int g   = r / 18432;
        int r2  = r % 18432;
        int tap = r2 / 2048;
        int r3  = r2 % 2048;
        int q   = r3 / 512;
        int r4  = r3 % 512;
        int co  = r4 / 8;
        int j   = r4 % 8;
        int ci = g * 32 + q * 8 + j;
        int base9 = (co * 64 + ci) * 9;
        int base3 = (co * 64 + ci) * 3;
        float v = 0.f;
        if (e == 0) {
            v = w1[base9 + tap];
        } else if (e == 1) {
            if (tap == 4) {
                float s = 0.f;
                #pragma unroll
                for (int k = 0; k < 9; k++) s += w_cd[base9 + k];
                v = w_cd[base9 + 4] - s;
            } else {
                v = w_cd[base9 + tap];
            }
        } else if (e == 2) {
            int m = tap % 3;
            if (m == 0) v = w_hd[base3 + tap / 3];
            else if (m == 2) v = -w_hd[base3 + tap / 3];
        } else if (e == 3) {
            if (tap < 3) v = w_vd[base3 + tap];
            else if (tap >= 6) v = -w_vd[base3 + tap - 6];
        } else {
            const int PERM[9] = {3, 0, 1, 6, 4, 2, 7, 8, 5};
            v = w_ad[base9 + tap] - w_ad[base9 + PERM[tap]];
        }
        wEffB[gid] = f2bf(v);
    } else if (gid < E_ * 36864 + E_ * 64) {
        int jj = gid - E_ * 36864;
        int e = jj / 64, co = jj % 64;
        const float* bs;
        switch (e) {
            case 0: bs = b1; break;
            case 1: bs = b_cd; break;
            case 2: bs = b_hd; break;
            case 3: bs = b_vd; break;
            default: bs = b_ad; break;
        }
        biasEff[jj] = bs[co];
    }
}

// ---------------------------------------------------------------------------
// Kernel 3: MFMA implicit-GEMM conv + exp + store + per-example Z sum
// grid: b(16) x rowgroup(32) x colhalf(2) = 1024 blocks, 256 thr (4 waves)
// [known-good 52 us version: A staged in LDS]
__global__ __launch_bounds__(256) void conv_mfma_kernel(
        const unsigned short* __restrict__ x_t, const unsigned short* __restrict__ wEffB,
        const float* __restrict__ biasEff, const int* __restrict__ expert_idx,
        unsigned short* __restrict__ expw, float* __restrict__ outf,
        float* __restrict__ Z, int direct_f32) {
    int bid = blockIdx.x;
    int b = bid >> 6;
    int rem = bid & 63;
    int rg = rem >> 1;        // 0..31, out rows rg*4..+3
    int ch = rem & 1;         // 0/1,  out cols ch*64..+63

    int t = threadIdx.x;
    int wave = t >> 6;        // out-row-local 0..3
    int lane = t & 63;
    int ln = lane & 15;
    int q = lane >> 4;

    int e = expert_idx[b];

    __shared__ __align__(16) unsigned short A_lds[9 * 4 * 66 * 8];  // 38016 B
    __shared__ __align__(16) unsigned short Xs[6 * 4 * 68 * 8];     // 26112 B
    __shared__ float zs[4];

    f32x4 acc[4][4];
    #pragma unroll
    for (int i = 0; i < 4; i++)
        #pragma unroll
        for (int jn = 0; jn < 4; jn++)
            acc[i][jn] = (f32x4){0.f, 0.f, 0.f, 0.f};

    const unsigned short* xb = x_t + (size_t)b * (128 * 128 * 64);
    const unsigned short* we = wEffB + (size_t)e * 36864;

    for (int g = 0; g < 2; g++) {
        // --- stage A: 2304 chunks of 16B ([tap][q][co][j], contiguous) ---
        const uint4* asrc = (const uint4*)(we + g * 18432);
        for (int j = t; j < 2304; j += 256) {
            int slotrow = j >> 6;     // tap*4 + q
            int m = j & 63;
            *(uint4*)&A_lds[(slotrow * 66 + m) * 8] = asrc[j];
        }
        // --- stage X: 6 rows x 66 cols x (4 q-chunks of 8 ci) ---
        for (int j = t; j < 1584; j += 256) {
            int xr = j / 264;
            int r2 = j % 264;
            int col = r2 >> 2;
            int qq = r2 & 3;
            int irow = rg * 4 - 1 + xr;
            int icol = ch * 64 - 1 + col;
            uint4 v = make_uint4(0, 0, 0, 0);
            if ((unsigned)irow < 128u && (unsigned)icol < 128u)
                v = *(const uint4*)(xb + ((size_t)irow * 128 + icol) * 64 + g * 32 + qq * 8);
            *(uint4*)&Xs[((xr * 4 + qq) * 68 + col) * 8] = v;
        }
        __syncthreads();

        #pragma unroll
        for (int tap = 0; tap < 9; tap++) {
            int dr = tap / 3, dc = tap % 3;
            bf16x8 af[4], bfr[4];
            #pragma unroll
            for (int mt = 0; mt < 4; mt++)
                af[mt] = *(const bf16x8*)&A_lds[((tap * 4 + q) * 66 + mt * 16 + ln) * 8];
            int xr = wave + dr;
            #pragma unroll
            for (int t4 = 0; t4 < 4; t4++)
                bfr[t4] = *(const bf16x8*)&Xs[((xr * 4 + q) * 68 + t4 * 16 + ln + dc) * 8];
            #pragma unroll
            for (int mt = 0; mt < 4; mt++)
                #pragma unroll
                for (int t4 = 0; t4 < 4; t4++)
                    acc[mt][t4] = __builtin_amdgcn_mfma_f32_16x16x32_bf16(
                        af[mt], bfr[t4], acc[mt][t4], 0, 0, 0);
        }
        __syncthreads();
    }

    // --- epilogue: bias + exp + store + Z reduction ---
    int orow = rg * 4 + wave;
    float bsum = 0.f;
    size_t obase = (size_t)b * (64 * 16384);
    #pragma unroll
    for (int mt = 0; mt < 4; mt++) {
        float4 bias4 = *(const float4*)(biasEff + e * 64 + mt * 16 + q * 4);
        const float* bp = (const float*)&bias4;
        #pragma unroll
        for (int r = 0; r < 4; r++) {
            int co = mt * 16 + q * 4 + r;
            size_t cb = obase + (size_t)co * 16384 + (size_t)orow * 128;
            #pragma unroll
            for (int t4 = 0; t4 < 4; t4++) {
                float ev = __expf(acc[mt][t4][r] + bp[r]);
                bsum += ev;
                int ocol = ch * 64 + t4 * 16 + ln;
                if (direct_f32) outf[cb + ocol] = ev;
                else            expw[cb + ocol] = f2bf(ev);
            }
        }
    }
    for (int off = 32; off; off >>= 1) bsum += __shfl_down(bsum, off, 64);
    if (lane == 0) zs[wave] = bsum;
    __syncthreads();
    if (t == 0) atomicAdd(&Z[b], zs[0] + zs[1] + zs[2] + zs[3]);
}

// ---------------------------------------------------------------------------
// Kernel 4a: out = bf16_exp * (1/Z[b]) -> fp32 (Mode A), grid-stride 2048 blocks
#define N_UINT4 2097152   // 16 * 64 * 16384 / 8
__global__ __launch_bounds__(256) void scale_bf16_kernel(
        const unsigned short* __restrict__ expw, const float* __restrict__ Z,
        float* __restrict__ out) {
    __shared__ float sinv[B_];
    if (threadIdx.x < B_) sinv[threadIdx.x] = 1.0f / Z[threadIdx.x];
    __syncthreads();
    for (int gid = blockIdx.x * 256 + threadIdx.x; gid < N_UINT4; gid += 2048 * 256) {
        int b = gid >> 17;                    // 131072 uint4 per example
        float s = sinv[b];
        uint4 r = ((const uint4*)expw)[gid];
        float4 o0, o1;
        o0.x = __uint_as_float(r.x << 16) * s;
        o0.y = __uint_as_float(r.x & 0xffff0000u) * s;
        o0.z = __uint_as_float(r.y << 16) * s;
        o0.w = __uint_as_float(r.y & 0xffff0000u) * s;
        o1.x = __uint_as_float(r.z << 16) * s;
        o1.y = __uint_as_float(r.z & 0xffff0000u) * s;
        o1.z = __uint_as_float(r.w << 16) * s;
        o1.w = __uint_as_float(r.w & 0xffff0000u) * s;
        ((float4*)out)[gid * 2] = o0;
        ((float4*)out)[gid * 2 + 1] = o1;
    }
}

// Kernel 4b: in-place out *= 1/Z[b] (Mode B), grid-stride
#define N_FLOAT4 4194304
__global__ __launch_bounds__(256) void scale_inplace_kernel(
        float* __restrict__ out, const float* __restrict__ Z) {
    __shared__ float sinv[B_];
    if (threadIdx.x < B_) sinv[threadIdx.x] = 1.0f / Z[threadIdx.x];
    __syncthreads();
    for (int gid = blockIdx.x * 256 + threadIdx.x; gid < N_FLOAT4; gid += 2048 * 256) {
        int b = gid >> 18;
        float s = sinv[b];
        float4 v = ((float4*)out)[gid];
        v.x *= s; v.y *= s; v.z *= s; v.w *= s;
        ((float4*)out)[gid] = v;
    }
}

// ---------------------------------------------------------------------------
extern "C" void kernel_launch(void* const* d_in, const int* in_sizes, int n_in,
                              void* d_out, int out_size, void* d_ws, size_t ws_size,
                              hipStream_t stream) {
    const float* x       = (const float*)d_in[0];
    const float* noise   = (const float*)d_in[1];
    const float* w_gate  = (const float*)d_in[2];
    const float* b_gate  = (const float*)d_in[3];
    const float* w_noise = (const float*)d_in[4];
    const float* b_noise = (const float*)d_in[5];
    const float* w1      = (const float*)d_in[6];
    const float* b1      = (const float*)d_in[7];
    const float* w_cd    = (const float*)d_in[8];
    const float* b_cd    = (const float*)d_in[9];
    const float* w_hd    = (const float*)d_in[10];
    const float* b_hd    = (const float*)d_in[11];
    const float* w_vd    = (const float*)d_in[12];
    const float* b_vd    = (const float*)d_in[13];
    const float* w_ad    = (const float*)d_in[14];
    const float* b_ad    = (const float*)d_in[15];

    char* ws = (char*)d_ws;
    unsigned short* wEffB   = (unsigned short*)(ws + WS_WEFFB);
    float*          biasEff = (float*)(ws + WS_BIAS);
    float*          pooled  = (float*)(ws + WS_POOL);
    float*          Zbuf    = (float*)(ws + WS_Z);
    int*            eidx    = (int*)(ws + WS_EIDX);
    unsigned short* x_t     = (unsigned short*)(ws + WS_XT);
    unsigned short* expw    = (unsigned short*)(ws + WS_EXP);

    float* out = (float*)d_out;
    int mode_a = (ws_size >= WS_NEED_A) ? 1 : 0;

    // zero pooled + Z (contiguous 4160 B)
    hipMemsetAsync(pooled, 0, 4160, stream);

    transpose_pool_kernel<<<B_ * 128, 256, 0, stream>>>(x, x_t, pooled);
    prep_kernel<<<B_ + 722, 256, 0, stream>>>(pooled, noise, w_gate, b_gate,
                                              w_noise, b_noise,
                                              w1, w_cd, w_hd, w_vd, w_ad,
                                              b1, b_cd, b_hd, b_vd, b_ad,
                                              eidx, wEffB, biasEff);
    conv_mfma_kernel<<<1024, 256, 0, stream>>>(x_t, wEffB, biasEff, eidx,
                                               expw, out, Zbuf, mode_a ? 0 : 1);
    if (mode_a)
        scale_bf16_kernel<<<2048, 256, 0, stream>>>(expw, Zbuf, out);
    else
        scale_inplace_kernel<<<2048, 256, 0, stream>>>(out, Zbuf);
}

// Round 4
// 215.440 us; speedup vs baseline: 1.1144x; 1.0218x over previous
//
#include <hip/hip_runtime.h>
#include <math.h>

#define B_  16
#define C_  64
#define E_  5

typedef __bf16  bf16x8 __attribute__((ext_vector_type(8)));
typedef float   f32x4  __attribute__((ext_vector_type(4)));

// ---- ws byte offsets ----
// wEffB: [e(5)][g(2)][tap(9)][q(4)][co(64)][j(8)] ushort = 184320 shorts = 368640 B
#define WS_WEFFB   0
#define WS_BIAS    368640      // float[5*64] -> ends 369920
#define WS_POOL    369920      // float[16*64] (zeroed each call) -> 374016
#define WS_Z       374016      // float[16] (zeroed each call) -> 374080
#define WS_EIDX    374080      // int[16] -> 374144
#define WS_XT      374144      // bf16 x_t [b][row][col][ci] = 33554432 B -> 33928576
#define WS_EXP     33928576ull // bf16 exp [b][co][row][col] = 33554432 B -> 67483008
#define WS_NEED_A  67483008ull

static __device__ __forceinline__ unsigned short f2bf(float f) {
    unsigned int u = __float_as_uint(f);
    unsigned int r = (u + 0x7fffu + ((u >> 16) & 1u)) >> 16;  // RNE
    return (unsigned short)r;
}

// ---------------------------------------------------------------------------
// Kernel 1: fused transpose (fp32 NCHW -> bf16 NHWC) + global-mean pooling
// grid: (b*128 + row) = 2048 blocks, 256 thr  [known-good]
__global__ __launch_bounds__(256) void transpose_pool_kernel(
        const float* __restrict__ x, unsigned short* __restrict__ x_t,
        float* __restrict__ pooled) {
    int bid = blockIdx.x;
    int b = bid >> 7, row = bid & 127;
    int t = threadIdx.x;
    int wave = t >> 6, l = t & 63;
    int half = l >> 5;        // which of 2 ci per iter
    int c4 = l & 31;          // float4 column chunk

    __shared__ unsigned short T[128][72];   // [col][ci], padded

    const float* xb = x + (size_t)b * (64 * 16384) + row * 128;

    #pragma unroll
    for (int it = 0; it < 8; it++) {
        int ci = wave * 16 + it * 2 + half;
        float4 v = *(const float4*)(xb + (size_t)ci * 16384 + c4 * 4);
        float p = v.x + v.y + v.z + v.w;
        p += __shfl_down(p, 16, 32);
        p += __shfl_down(p, 8, 32);
        p += __shfl_down(p, 4, 32);
        p += __shfl_down(p, 2, 32);
        p += __shfl_down(p, 1, 32);
        if (c4 == 0) atomicAdd(&pooled[b * 64 + ci], p * (1.0f / 16384.0f));
        int colb = c4 * 4;
        T[colb + 0][ci] = f2bf(v.x);
        T[colb + 1][ci] = f2bf(v.y);
        T[colb + 2][ci] = f2bf(v.z);
        T[colb + 3][ci] = f2bf(v.w);
    }
    __syncthreads();

    unsigned short* dst = x_t + ((size_t)(b * 128 + row) * 128) * 64;
    #pragma unroll
    for (int k = 0; k < 4; k++) {
        int chunk = t + k * 256;          // 1024 chunks of 16B
        int col = chunk >> 3, c8 = chunk & 7;
        uint4 vv = *(const uint4*)&T[col][c8 * 8];
        *(uint4*)(dst + col * 64 + c8 * 8) = vv;
    }
}

// ---------------------------------------------------------------------------
// Kernel 2: fused routing (blocks 0..15, lane-parallel) + build_w (blocks 16+)
// grid: 16 + 722 = 738 blocks, 256 thr
__global__ __launch_bounds__(256) void prep_kernel(
        const float* __restrict__ pooled, const float* __restrict__ noise,
        const float* __restrict__ w_gate, const float* __restrict__ b_gate,
        const float* __restrict__ w_noise, const float* __restrict__ b_noise,
        const float* __restrict__ w1, const float* __restrict__ w_cd,
        const float* __restrict__ w_hd, const float* __restrict__ w_vd,
        const float* __restrict__ w_ad,
        const float* __restrict__ b1, const float* __restrict__ b_cd,
        const float* __restrict__ b_hd, const float* __restrict__ b_vd,
        const float* __restrict__ b_ad,
        int* __restrict__ expert_idx,
        unsigned short* __restrict__ wEffB, float* __restrict__ biasEff) {
    int blk = blockIdx.x;
    int t = threadIdx.x;

    if (blk < B_) {
        // ---- routing for example b = blk: lanes 0..63 parallel over channels ----
        if (t < 64) {
            int b = blk;
            float pv = pooled[b * C_ + t];
            float ge[E_], ne[E_];
            #pragma unroll
            for (int e = 0; e < E_; e++) {
                ge[e] = pv * w_gate[t * E_ + e];
                ne[e] = pv * w_noise[t * E_ + e];
            }
            #pragma unroll
            for (int off = 32; off; off >>= 1) {
                #pragma unroll
                for (int e = 0; e < E_; e++) {
                    ge[e] += __shfl_xor(ge[e], off, 64);
                    ne[e] += __shfl_xor(ne[e], off, 64);
                }
            }
            if (t == 0) {
                float best = -1e30f; int bi = 0;
                #pragma unroll
                for (int e = 0; e < E_; e++) {
                    float lg = ge[e] + b_gate[e];
                    float nz = ne[e] + b_noise[e];
                    float sp = log1pf(expf(nz));
                    float v = lg + noise[b * E_ + e] * sp;
                    if (v > best) { best = v; bi = e; }   // first max wins (matches top_k)
                }
                expert_idx[b] = bi;
            }
        }
        return;
    }

    // ---- build effective weights ----
    int gid = (blk - B_) * 256 + t;
    if (gid < E_ * 36864) {
        int e   = gid / 36864;
        int r   = gid % 36864;
        int g   = r / 18432;
        int r2  = r % 18432;
        int tap = r2 / 2048;
        int r3  = r2 % 2048;
        int q   = r3 / 512;
        int r4  = r3 % 512;
        int co  = r4 / 8;
        int j   = r4 % 8;
        int ci = g * 32 + q * 8 + j;
        int base9 = (co * 64 + ci) * 9;
        int base3 = (co * 64 + ci) * 3;
        float v = 0.f;
        if (e == 0) {
            v = w1[base9 + tap];
        } else if (e == 1) {
            if (tap == 4) {
                float s = 0.f;
                #pragma unroll
                for (int k = 0; k < 9; k++) s += w_cd[base9 + k];
                v = w_cd[base9 + 4] - s;
            } else {
                v = w_cd[base9 + tap];
            }
        } else if (e == 2) {
            int m = tap % 3;
            if (m == 0) v = w_hd[base3 + tap / 3];
            else if (m == 2) v = -w_hd[base3 + tap / 3];
        } else if (e == 3) {
            if (tap < 3) v = w_vd[base3 + tap];
            else if (tap >= 6) v = -w_vd[base3 + tap - 6];
        } else {
            const int PERM[9] = {3, 0, 1, 6, 4, 2, 7, 8, 5};
            v = w_ad[base9 + tap] - w_ad[base9 + PERM[tap]];
        }
        wEffB[gid] = f2bf(v);
    } else if (gid < E_ * 36864 + E_ * 64) {
        int jj = gid - E_ * 36864;
        int e = jj / 64, co = jj % 64;
        const float* bs;
        switch (e) {
            case 0: bs = b1; break;
            case 1: bs = b_cd; break;
            case 2: bs = b_hd; break;
            case 3: bs = b_vd; break;
            default: bs = b_ad; break;
        }
        biasEff[jj] = bs[co];
    }
}

// ---------------------------------------------------------------------------
// Kernel 3: MFMA implicit-GEMM conv + exp + store + per-example Z sum
// grid: b(16) x rowgroup(32) x colhalf(2) = 1024 blocks, 256 thr (4 waves)
// A staged in LDS in 3-tap chunks (12.4 KiB) -> total LDS ~38.8 KiB -> 4 blk/CU,
// grid exactly co-resident (1024 = 4*256), barriers overlap across blocks.
__global__ __launch_bounds__(256, 4) void conv_mfma_kernel(
        const unsigned short* __restrict__ x_t, const unsigned short* __restrict__ wEffB,
        const float* __restrict__ biasEff, const int* __restrict__ expert_idx,
        unsigned short* __restrict__ expw, float* __restrict__ outf,
        float* __restrict__ Z, int direct_f32) {
    int bid = blockIdx.x;
    int b = bid >> 6;
    int rem = bid & 63;
    int rg = rem >> 1;        // 0..31, out rows rg*4..+3
    int ch = rem & 1;         // 0/1,  out cols ch*64..+63

    int t = threadIdx.x;
    int wave = t >> 6;        // out-row-local 0..3
    int lane = t & 63;
    int ln = lane & 15;
    int q = lane >> 4;

    int e = expert_idx[b];

    __shared__ __align__(16) unsigned short A_lds[3 * 4 * 66 * 8];  // 12672 B (3-tap chunk)
    __shared__ __align__(16) unsigned short Xs[6 * 4 * 68 * 8];     // 26112 B
    __shared__ float zs[4];

    f32x4 acc[4][4];
    #pragma unroll
    for (int i = 0; i < 4; i++)
        #pragma unroll
        for (int jn = 0; jn < 4; jn++)
            acc[i][jn] = (f32x4){0.f, 0.f, 0.f, 0.f};

    const unsigned short* xb = x_t + (size_t)b * (128 * 128 * 64);
    const unsigned short* we = wEffB + (size_t)e * 36864;

    for (int g = 0; g < 2; g++) {
        // --- stage X: 6 rows x 66 cols x (4 q-chunks of 8 ci) ---
        for (int j = t; j < 1584; j += 256) {
            int xr = j / 264;
            int r2 = j % 264;
            int col = r2 >> 2;
            int qq = r2 & 3;
            int irow = rg * 4 - 1 + xr;
            int icol = ch * 64 - 1 + col;
            uint4 v = make_uint4(0, 0, 0, 0);
            if ((unsigned)irow < 128u && (unsigned)icol < 128u)
                v = *(const uint4*)(xb + ((size_t)irow * 128 + icol) * 64 + g * 32 + qq * 8);
            *(uint4*)&Xs[((xr * 4 + qq) * 68 + col) * 8] = v;
        }

        const uint4* asrc = (const uint4*)(we + g * 18432);
        #pragma unroll
        for (int chunk = 0; chunk < 3; chunk++) {
            // --- stage A chunk: 3 taps = 768 x 16B ([tap_local][q][co][j]) ---
            #pragma unroll
            for (int k = 0; k < 3; k++) {
                int j = t + k * 256;              // 0..767
                int slotrow = j >> 6;             // tap_local*4 + q, 0..11
                int m = j & 63;
                *(uint4*)&A_lds[(slotrow * 66 + m) * 8] = asrc[chunk * 768 + j];
            }
            __syncthreads();    // A chunk (and, for chunk 0, X) visible

            // taps chunk*3 .. chunk*3+2: dr = chunk, dc = tl
            int xr = wave + chunk;
            #pragma unroll
            for (int tl = 0; tl < 3; tl++) {
                bf16x8 af[4], bfr[4];
                #pragma unroll
                for (int mt = 0; mt < 4; mt++)
                    af[mt] = *(const bf16x8*)&A_lds[((tl * 4 + q) * 66 + mt * 16 + ln) * 8];
                #pragma unroll
                for (int t4 = 0; t4 < 4; t4++)
                    bfr[t4] = *(const bf16x8*)&Xs[((xr * 4 + q) * 68 + t4 * 16 + ln + tl) * 8];
                #pragma unroll
                for (int mt = 0; mt < 4; mt++)
                    #pragma unroll
                    for (int t4 = 0; t4 < 4; t4++)
                        acc[mt][t4] = __builtin_amdgcn_mfma_f32_16x16x32_bf16(
                            af[mt], bfr[t4], acc[mt][t4], 0, 0, 0);
            }
            __syncthreads();    // WAR: compute done before next A stage / X overwrite
        }
    }

    // --- epilogue: bias + exp + store + Z reduction ---
    int orow = rg * 4 + wave;
    float bsum = 0.f;
    size_t obase = (size_t)b * (64 * 16384);
    #pragma unroll
    for (int mt = 0; mt < 4; mt++) {
        float4 bias4 = *(const float4*)(biasEff + e * 64 + mt * 16 + q * 4);
        const float* bp = (const float*)&bias4;
        #pragma unroll
        for (int r = 0; r < 4; r++) {
            int co = mt * 16 + q * 4 + r;
            size_t cb = obase + (size_t)co * 16384 + (size_t)orow * 128;
            #pragma unroll
            for (int t4 = 0; t4 < 4; t4++) {
                float ev = __expf(acc[mt][t4][r] + bp[r]);
                bsum += ev;
                int ocol = ch * 64 + t4 * 16 + ln;
                if (direct_f32) outf[cb + ocol] = ev;
                else            expw[cb + ocol] = f2bf(ev);
            }
        }
    }
    for (int off = 32; off; off >>= 1) bsum += __shfl_down(bsum, off, 64);
    if (lane == 0) zs[wave] = bsum;
    __syncthreads();
    if (t == 0) atomicAdd(&Z[b], zs[0] + zs[1] + zs[2] + zs[3]);
}

// ---------------------------------------------------------------------------
// Kernel 4a: out = bf16_exp * (1/Z[b]) -> fp32 (Mode A), grid-stride 2048 blocks
#define N_UINT4 2097152   // 16 * 64 * 16384 / 8
__global__ __launch_bounds__(256) void scale_bf16_kernel(
        const unsigned short* __restrict__ expw, const float* __restrict__ Z,
        float* __restrict__ out) {
    __shared__ float sinv[B_];
    if (threadIdx.x < B_) sinv[threadIdx.x] = 1.0f / Z[threadIdx.x];
    __syncthreads();
    for (int gid = blockIdx.x * 256 + threadIdx.x; gid < N_UINT4; gid += 2048 * 256) {
        int b = gid >> 17;                    // 131072 uint4 per example
        float s = sinv[b];
        uint4 r = ((const uint4*)expw)[gid];
        float4 o0, o1;
        o0.x = __uint_as_float(r.x << 16) * s;
        o0.y = __uint_as_float(r.x & 0xffff0000u) * s;
        o0.z = __uint_as_float(r.y << 16) * s;
        o0.w = __uint_as_float(r.y & 0xffff0000u) * s;
        o1.x = __uint_as_float(r.z << 16) * s;
        o1.y = __uint_as_float(r.z & 0xffff0000u) * s;
        o1.z = __uint_as_float(r.w << 16) * s;
        o1.w = __uint_as_float(r.w & 0xffff0000u) * s;
        ((float4*)out)[gid * 2] = o0;
        ((float4*)out)[gid * 2 + 1] = o1;
    }
}

// Kernel 4b: in-place out *= 1/Z[b] (Mode B), grid-stride
#define N_FLOAT4 4194304
__global__ __launch_bounds__(256) void scale_inplace_kernel(
        float* __restrict__ out, const float* __restrict__ Z) {
    __shared__ float sinv[B_];
    if (threadIdx.x < B_) sinv[threadIdx.x] = 1.0f / Z[threadIdx.x];
    __syncthreads();
    for (int gid = blockIdx.x * 256 + threadIdx.x; gid < N_FLOAT4; gid += 2048 * 256) {
        int b = gid >> 18;
        float s = sinv[b];
        float4 v = ((float4*)out)[gid];
        v.x *= s; v.y *= s; v.z *= s; v.w *= s;
        ((float4*)out)[gid] = v;
    }
}

// ---------------------------------------------------------------------------
extern "C" void kernel_launch(void* const* d_in, const int* in_sizes, int n_in,
                              void* d_out, int out_size, void* d_ws, size_t ws_size,
                              hipStream_t stream) {
    const float* x       = (const float*)d_in[0];
    const float* noise   = (const float*)d_in[1];
    const float* w_gate  = (const float*)d_in[2];
    const float* b_gate  = (const float*)d_in[3];
    const float* w_noise = (const float*)d_in[4];
    const float* b_noise = (const float*)d_in[5];
    const float* w1      = (const float*)d_in[6];
    const float* b1      = (const float*)d_in[7];
    const float* w_cd    = (const float*)d_in[8];
    const float* b_cd    = (const float*)d_in[9];
    const float* w_hd    = (const float*)d_in[10];
    const float* b_hd    = (const float*)d_in[11];
    const float* w_vd    = (const float*)d_in[12];
    const float* b_vd    = (const float*)d_in[13];
    const float* w_ad    = (const float*)d_in[14];
    const float* b_ad    = (const float*)d_in[15];

    char* ws = (char*)d_ws;
    unsigned short* wEffB   = (unsigned short*)(ws + WS_WEFFB);
    float*          biasEff = (float*)(ws + WS_BIAS);
    float*          pooled  = (float*)(ws + WS_POOL);
    float*          Zbuf    = (float*)(ws + WS_Z);
    int*            eidx    = (int*)(ws + WS_EIDX);
    unsigned short* x_t     = (unsigned short*)(ws + WS_XT);
    unsigned short* expw    = (unsigned short*)(ws + WS_EXP);

    float* out = (float*)d_out;
    int mode_a = (ws_size >= WS_NEED_A) ? 1 : 0;

    // zero pooled + Z (contiguous 4160 B)
    hipMemsetAsync(pooled, 0, 4160, stream);

    transpose_pool_kernel<<<B_ * 128, 256, 0, stream>>>(x, x_t, pooled);
    prep_kernel<<<B_ + 722, 256, 0, stream>>>(pooled, noise, w_gate, b_gate,
                                              w_noise, b_noise,
                                              w1, w_cd, w_hd, w_vd, w_ad,
                                              b1, b_cd, b_hd, b_vd, b_ad,
                                              eidx, wEffB, biasEff);
    conv_mfma_kernel<<<1024, 256, 0, stream>>>(x_t, wEffB, biasEff, eidx,
                                               expw, out, Zbuf, mode_a ? 0 : 1);
    if (mode_a)
        scale_bf16_kernel<<<2048, 256, 0, stream>>>(expw, Zbuf, out);
    else
        scale_inplace_kernel<<<2048, 256, 0, stream>>>(out, Zbuf);
}